// Round 13
// baseline (206.687 us; speedup 1.0000x reference)
//
#include <hip/hip_runtime.h>
#include <hip/hip_bf16.h>
#include <hip/hip_fp16.h>

#define NN 100000
#define NE 1600000
#define FI 80
#define HD 64
#define NBUK 196   // ceil(NN/512) buckets of 512 nodes
#define BSH 9      // 512 nodes per bucket
#define NBLKA 391  // partition blocks; NBLKA*EPB >= NE
#define EPB 4096   // edges per partition block

typedef _Float16 f16x8 __attribute__((ext_vector_type(8)));
typedef float f32x4 __attribute__((ext_vector_type(4)));

// ---------------- fused weight precompute ----------------
// Wc_t[j][k] (fp16, [128][96], k>=80 zero): j<64: (Wz@lzW[0:64])[k][j]; j>=64: (Wh@lhW[0:64])[k][j-64]
// W1_t[j][k] (fp16, [128][64]): j<64: W1[k][j]; j>=64: W1[64+k][j-64]  (mlp_W1 is (128,64), stride 64)
// bzp/bhp = fused gate biases (f32).  (H=0 => R-gate dead; softmax(1)=1 => attention dead)
__global__ void fuse_weights(const float* __restrict__ Wz, const float* __restrict__ bz,
                             const float* __restrict__ lzW, const float* __restrict__ lzb,
                             const float* __restrict__ Wh, const float* __restrict__ bh,
                             const float* __restrict__ lhW, const float* __restrict__ lhb,
                             const float* __restrict__ W1,
                             _Float16* __restrict__ Wct, _Float16* __restrict__ W1t,
                             float* __restrict__ bzp, float* __restrict__ bhp) {
    int j = blockIdx.x;      // 0..127 output col
    int k = threadIdx.x;     // 0..127
    if (blockIdx.y == 1) {
        if (k < HD) {
            float v = (j < HD) ? W1[k * HD + j] : W1[(HD + k) * HD + (j - HD)];
            W1t[j * HD + k] = (_Float16)v;
        }
        return;
    }
    bool isZ = j < 64;
    int jj = isZ ? j : j - 64;
    const float* W = isZ ? Wz : Wh;
    const float* L = isZ ? lzW : lhW;
    if (k < FI) {
        float acc = 0.f;
        for (int i = 0; i < HD; ++i) acc = fmaf(W[k * HD + i], L[i * HD + jj], acc);
        Wct[j * 96 + k] = (_Float16)acc;
    } else if (k < 96) {
        Wct[j * 96 + k] = (_Float16)0.f;
    } else if (k == 96) {
        const float* bb = isZ ? bz : bh;
        const float* lb = isZ ? lzb : lhb;
        float acc = lb[jj];
        for (int i = 0; i < HD; ++i) acc = fmaf(bb[i], L[i * HD + jj], acc);
        (isZ ? bzp : bhp)[jj] = acc;
    }
}

// ---------------- radix-partition CSR build: ZERO global atomics ----------------
// (R11 diag: random returning atomics cap at ~25 Gops/s device-wide regardless of layout.)

// K1: per-block bucket histogram
__global__ __launch_bounds__(256) void bucket_count(const int* __restrict__ gdst,
                                                    unsigned* __restrict__ blockcounts) {
    __shared__ unsigned lcnt[NBUK];
    for (int i = threadIdx.x; i < NBUK; i += 256) lcnt[i] = 0;
    __syncthreads();
    int base = blockIdx.x * EPB;
#pragma unroll
    for (int i = 0; i < EPB / 256; ++i) {
        int e = base + i * 256 + threadIdx.x;
        if (e < NE) atomicAdd(&lcnt[(unsigned)gdst[e] >> BSH], 1u);
    }
    __syncthreads();
    for (int i = threadIdx.x; i < NBUK; i += 256)
        blockcounts[i * NBLKA + blockIdx.x] = lcnt[i];   // bucket-major
}

// K2a: per-bucket exclusive scan over blocks; emit bucket totals
__global__ __launch_bounds__(512) void bucket_scan_a(unsigned* __restrict__ blockcounts,
                                                     unsigned* __restrict__ buktot) {
    __shared__ unsigned s[512];
    int b = blockIdx.x, t = threadIdx.x;
    unsigned v = (t < NBLKA) ? blockcounts[b * NBLKA + t] : 0;
    s[t] = v;
    __syncthreads();
    for (int off = 1; off < 512; off <<= 1) {
        unsigned x = 0;
        if (t >= off) x = s[t - off];
        __syncthreads();
        s[t] += x;
        __syncthreads();
    }
    if (t < NBLKA) blockcounts[b * NBLKA + t] = s[t] - v;   // exclusive within bucket
    if (t == 511) buktot[b] = s[511];
}

// K2b: exclusive scan of bucket totals -> bukstart[0..NBUK]
__global__ void bucket_scan_b(const unsigned* __restrict__ buktot, unsigned* __restrict__ bukstart) {
    __shared__ unsigned s[256];
    int t = threadIdx.x;
    unsigned v = (t < NBUK) ? buktot[t] : 0;
    s[t] = v;
    __syncthreads();
    for (int off = 1; off < 256; off <<= 1) {
        unsigned x = 0;
        if (t >= off) x = s[t - off];
        __syncthreads();
        s[t] += x;
        __syncthreads();
    }
    if (t < NBUK) bukstart[t] = s[t] - v;
    if (t == NBUK - 1) bukstart[NBUK] = s[t];   // == NE
}

// K3: partition edges into bucket segments. payload: dl[9] | src[17] | ew_q20[20]
__global__ __launch_bounds__(256) void bucket_scatter(const int* __restrict__ gsrc,
                                                      const int* __restrict__ gdst,
                                                      const float* __restrict__ ew,
                                                      const unsigned* __restrict__ blockcounts,
                                                      const unsigned* __restrict__ bukstart,
                                                      unsigned long long* __restrict__ bedges) {
    __shared__ unsigned cur[NBUK];
    for (int i = threadIdx.x; i < NBUK; i += 256)
        cur[i] = bukstart[i] + blockcounts[i * NBLKA + blockIdx.x];
    __syncthreads();
    int base = blockIdx.x * EPB;
#pragma unroll
    for (int i = 0; i < EPB / 256; ++i) {
        int e = base + i * 256 + threadIdx.x;
        if (e < NE) {
            unsigned d = (unsigned)gdst[e];
            unsigned b = d >> BSH;
            unsigned pos = atomicAdd(&cur[b], 1u);                    // LDS atomic
            unsigned q20 = (unsigned)(ew[e] * 1048575.0f);            // floor, no src-field bleed
            unsigned long long pay = ((unsigned long long)(d & 511u) << 37) |
                                     ((unsigned long long)(unsigned)gsrc[e] << 20) |
                                     (unsigned long long)q20;
            bedges[pos] = pay;
        }
    }
}

// K4: per-bucket CSR build: LDS histogram+degsum -> LDS scan -> LDS-cursor scatter
__global__ __launch_bounds__(512) void csr_build(const unsigned long long* __restrict__ bedges,
                                                 const unsigned* __restrict__ bukstart,
                                                 unsigned* __restrict__ csr,
                                                 float* __restrict__ dinv,
                                                 int* __restrict__ cnt,
                                                 int* __restrict__ rowstart) {
    __shared__ unsigned lcnt[512];
    __shared__ unsigned ldeg[512];   // q20 fixed-point degree sum
    __shared__ unsigned lrow[512];
    int b = blockIdx.x, t = threadIdx.x;
    lcnt[t] = 0;
    ldeg[t] = 0;
    __syncthreads();
    unsigned beg = bukstart[b], end = bukstart[b + 1];
    for (unsigned i = beg + t; i < end; i += 512) {
        unsigned long long p = bedges[i];
        unsigned dl = (unsigned)(p >> 37);
        atomicAdd(&lcnt[dl], 1u);
        atomicAdd(&ldeg[dl], (unsigned)(p & 0xFFFFFu));
    }
    __syncthreads();
    unsigned v = lcnt[t];
    lrow[t] = v;
    __syncthreads();
    for (int off = 1; off < 512; off <<= 1) {
        unsigned x = 0;
        if (t >= off) x = lrow[t - off];
        __syncthreads();
        lrow[t] += x;
        __syncthreads();
    }
    unsigned myrow = lrow[t] - v;   // exclusive, bucket-relative
    __syncthreads();
    lrow[t] = beg + myrow;          // global cursor
    __syncthreads();
    for (unsigned i = beg + t; i < end; i += 512) {
        unsigned long long p = bedges[i];
        unsigned dl = (unsigned)(p >> 37);
        unsigned src = (unsigned)((p >> 20) & 0x1FFFFu);
        unsigned q15 = ((unsigned)(p & 0xFFFFFu)) >> 5;    // <= 32767
        unsigned pos = atomicAdd(&lrow[dl], 1u);           // LDS atomic
        csr[pos] = (src << 15) | q15;
    }
    int node = (b << BSH) + t;
    if (node < NN) {
        float deg = 1.0f + (float)ldeg[t] * (1.0f / 1048576.0f);
        dinv[node] = rsqrtf(deg);
        cnt[node] = (int)lcnt[t];
        rowstart[node] = (int)(beg + myrow);
    }
}

// ---------------- y table: y[n] = dinv[n]*x[n], fp16, rows padded to 96 halves ----------------
__global__ void build_y(const float* __restrict__ x, const float* __restrict__ dinv,
                        ushort* __restrict__ yh) {
    int i = blockIdx.x * 256 + threadIdx.x;   // over NN*48 half2
    if (i >= NN * 48) return;
    int n = i / 48, p = i % 48;
    float di = dinv[n];
    __half2 h;
    if (p < 40) {
        float2 vv = *(const float2*)(x + (size_t)n * FI + 2 * p);
        h = __floats2half2_rn(di * vv.x, di * vv.y);
    } else {
        h = __floats2half2_rn(0.f, 0.f);
    }
    *(__half2*)(yh + (size_t)n * 96 + 2 * p) = h;
}

// ---------------- gather aggregation: TWO nodes per 8-lane group (dual gather chains) ----------------
// (R12 diag: ~1 row in flight per wave, MLP-starved 2.5x vs Little's law)
#define HALFN (NN / 2)
__global__ __launch_bounds__(256) void gather_agg(const int* __restrict__ rowstart,
                                                  const int* __restrict__ cnt,
                                                  const unsigned* __restrict__ csr,
                                                  const float* __restrict__ dinv,
                                                  const ushort* __restrict__ yh,
                                                  ushort* __restrict__ aggh) {
    int t = blockIdx.x * 256 + threadIdx.x;
    int g = t >> 3, k = t & 7;
    if (g >= HALFN) return;
    int n0 = g, n1 = g + HALFN;

    float di0 = dinv[n0], di1 = dinv[n1];
    const ushort* yn0 = yh + (size_t)n0 * 96;
    const ushort* yn1 = yh + (size_t)n1 * 96;
    float2 acc0[5], acc1[5];
#pragma unroll
    for (int j = 0; j < 5; ++j) {
        acc0[j] = __half22float2(*(const __half2*)(yn0 + 2 * k + 16 * j));
        acc1[j] = __half22float2(*(const __half2*)(yn1 + 2 * k + 16 * j));
    }
    int i0 = rowstart[n0], e0 = i0 + cnt[n0];
    int i1 = rowstart[n1], e1 = i1 + cnt[n1];
    unsigned p0 = (i0 < e0) ? csr[i0] : 0u;
    unsigned p1 = (i1 < e1) ? csr[i1] : 0u;

    // dual-chain main loop
    while (i0 < e0 && i1 < e1) {
        unsigned c0 = p0, c1 = p1;
        if (i0 + 1 < e0) p0 = csr[i0 + 1];
        if (i1 + 1 < e1) p1 = csr[i1 + 1];
        const ushort* ys0 = yh + (size_t)(c0 >> 15) * 96;
        const ushort* ys1 = yh + (size_t)(c1 >> 15) * 96;
        float w0 = (float)(c0 & 0x7FFFu) * (1.0f / 32767.0f);
        float w1 = (float)(c1 & 0x7FFFu) * (1.0f / 32767.0f);
        __half2 v0[5], v1[5];
#pragma unroll
        for (int j = 0; j < 5; ++j) {
            v0[j] = *(const __half2*)(ys0 + 2 * k + 16 * j);
            v1[j] = *(const __half2*)(ys1 + 2 * k + 16 * j);
        }
#pragma unroll
        for (int j = 0; j < 5; ++j) {
            float2 f0 = __half22float2(v0[j]);
            float2 f1 = __half22float2(v1[j]);
            acc0[j].x = fmaf(w0, f0.x, acc0[j].x);
            acc0[j].y = fmaf(w0, f0.y, acc0[j].y);
            acc1[j].x = fmaf(w1, f1.x, acc1[j].x);
            acc1[j].y = fmaf(w1, f1.y, acc1[j].y);
        }
        ++i0; ++i1;
    }
    // drain chain 0
    while (i0 < e0) {
        unsigned c0 = p0;
        if (i0 + 1 < e0) p0 = csr[i0 + 1];
        const ushort* ys0 = yh + (size_t)(c0 >> 15) * 96;
        float w0 = (float)(c0 & 0x7FFFu) * (1.0f / 32767.0f);
#pragma unroll
        for (int j = 0; j < 5; ++j) {
            float2 f0 = __half22float2(*(const __half2*)(ys0 + 2 * k + 16 * j));
            acc0[j].x = fmaf(w0, f0.x, acc0[j].x);
            acc0[j].y = fmaf(w0, f0.y, acc0[j].y);
        }
        ++i0;
    }
    // drain chain 1
    while (i1 < e1) {
        unsigned c1 = p1;
        if (i1 + 1 < e1) p1 = csr[i1 + 1];
        const ushort* ys1 = yh + (size_t)(c1 >> 15) * 96;
        float w1 = (float)(c1 & 0x7FFFu) * (1.0f / 32767.0f);
#pragma unroll
        for (int j = 0; j < 5; ++j) {
            float2 f1 = __half22float2(*(const __half2*)(ys1 + 2 * k + 16 * j));
            acc1[j].x = fmaf(w1, f1.x, acc1[j].x);
            acc1[j].y = fmaf(w1, f1.y, acc1[j].y);
        }
        ++i1;
    }
    ushort* an0 = aggh + (size_t)n0 * FI;
    ushort* an1 = aggh + (size_t)n1 * FI;
#pragma unroll
    for (int j = 0; j < 5; ++j) {
        *(__half2*)(an0 + 2 * k + 16 * j) = __floats2half2_rn(di0 * acc0[j].x, di0 * acc0[j].y);
        *(__half2*)(an1 + 2 * k + 16 * j) = __floats2half2_rn(di1 * acc1[j].x, di1 * acc1[j].y);
    }
}

// ---------------- node kernel: MFMA fp16 two-stage GEMM ----------------
// GEMM1: u(16x80,fp16) @ Wc(80x128) -> gates -> h(16x64);  GEMM2: h @ W1(64x128) -> ab fp16
// C-layout: col=lane&15, row=(lane>>4)*4+r (m89-verified); k-perm consistent on A/B sides.
__global__ __launch_bounds__(256) void node_kernel(const ushort* __restrict__ aggh,
        const _Float16* __restrict__ Wct, const _Float16* __restrict__ W1t,
        const float* __restrict__ bzp, const float* __restrict__ bhp,
        const float* __restrict__ b1, ushort* __restrict__ abh) {
    __shared__ __align__(16) _Float16 sWc[128 * 104];
    __shared__ __align__(16) _Float16 sW1[128 * 72];
    __shared__ __align__(16) _Float16 wbuf[4][2176];
    int tid = threadIdx.x;
    for (int i = tid; i < 1536; i += 256) {
        int col = i / 12, ko = (i % 12) * 8;
        *(uint4*)&sWc[col * 104 + ko] = ((const uint4*)Wct)[i];
    }
    for (int i = tid; i < 1024; i += 256) {
        int col = i / 8, ko = (i % 8) * 8;
        *(uint4*)&sW1[col * 72 + ko] = ((const uint4*)W1t)[i];
    }
    __syncthreads();

    int lane = tid & 63, wv = tid >> 6;
    int q = lane & 15, kg = lane >> 4;
    _Float16* hwb = wbuf[wv];

    float bzc[4], bhc[4], b1c[4];
#pragma unroll
    for (int t = 0; t < 4; ++t) {
        bzc[t] = bzp[q + 16 * t];
        bhc[t] = bhp[q + 16 * t];
        b1c[t] = b1[q + 16 * t];
    }

    const int NT = (NN + 63) >> 6;
    for (int tile = blockIdx.x; tile < NT; tile += gridDim.x) {
        int m0 = tile * 64 + wv * 16;
        int node = m0 + q;
        bool rv = node < NN;
        const _Float16* up = (const _Float16*)(aggh + (size_t)node * FI);
        f16x8 a1[3];
#pragma unroll
        for (int ks = 0; ks < 3; ++ks) {
            int kk = ks * 32 + kg * 8;
            a1[ks] = (rv && kk < FI) ? *(const f16x8*)(up + kk) : f16x8{};
        }
        f32x4 acc[8];
#pragma unroll
        for (int t = 0; t < 8; ++t) {
            const _Float16* wp = &sWc[(q + 16 * t) * 104 + kg * 8];
            f32x4 a = {0.f, 0.f, 0.f, 0.f};
            a = __builtin_amdgcn_mfma_f32_16x16x32_f16(a1[0], *(const f16x8*)(wp), a, 0, 0, 0);
            a = __builtin_amdgcn_mfma_f32_16x16x32_f16(a1[1], *(const f16x8*)(wp + 32), a, 0, 0, 0);
            a = __builtin_amdgcn_mfma_f32_16x16x32_f16(a1[2], *(const f16x8*)(wp + 64), a, 0, 0, 0);
            acc[t] = a;
        }
#pragma unroll
        for (int t = 0; t < 4; ++t) {
#pragma unroll
            for (int r = 0; r < 4; ++r) {
                float z = acc[t][r] + bzc[t];
                float p = acc[t + 4][r] + bhc[t];
                float Z = 1.f / (1.f + __expf(-z));
                float p2 = fminf(fmaxf(2.f * p, -60.f), 60.f);
                float e2 = __expf(p2);
                float Ht = (e2 - 1.f) / (e2 + 1.f);
                hwb[(kg * 4 + r) * 72 + q + 16 * t] = (_Float16)((1.f - Z) * Ht);
            }
        }
        f16x8 a2[2];
        a2[0] = *(const f16x8*)&hwb[q * 72 + kg * 8];
        a2[1] = *(const f16x8*)&hwb[q * 72 + 32 + kg * 8];
#pragma unroll
        for (int t = 0; t < 8; ++t) {
            const _Float16* wp = &sW1[(q + 16 * t) * 72 + kg * 8];
            f32x4 a = {0.f, 0.f, 0.f, 0.f};
            a = __builtin_amdgcn_mfma_f32_16x16x32_f16(a2[0], *(const f16x8*)(wp), a, 0, 0, 0);
            a = __builtin_amdgcn_mfma_f32_16x16x32_f16(a2[1], *(const f16x8*)(wp + 32), a, 0, 0, 0);
            float bb = (t < 4) ? b1c[t] : 0.f;
#pragma unroll
            for (int r = 0; r < 4; ++r)
                hwb[(kg * 4 + r) * 136 + q + 16 * t] = (_Float16)(a[r] + bb);
        }
#pragma unroll
        for (int i = lane; i < 256; i += 64) {
            int nd = i >> 4, off = (i & 15) * 8;
            int n2 = m0 + nd;
            if (n2 < NN)
                *(uint4*)(abh + (size_t)n2 * 128 + off) = *(const uint4*)&hwb[nd * 136 + off];
        }
    }
}

// ---------------- edge classifier: 8 lanes/edge, FOUR edges per group (8 gather chains) ----------------
__global__ __launch_bounds__(256) void edge_kernel(const ushort* __restrict__ abh,
                                                   const int* __restrict__ esrc, const int* __restrict__ edst,
                                                   const float* __restrict__ W2, const float* __restrict__ b2,
                                                   float* __restrict__ out) {
    const int QTR = NE / 4;
    int t = blockIdx.x * 256 + threadIdx.x;
    int g = t >> 3, q = t & 7;
    if (g >= QTR) return;
    int e[4] = {g, g + QTR, g + 2 * QTR, g + 3 * QTR};
    uint4 av[4], bv[4];
#pragma unroll
    for (int m = 0; m < 4; ++m) {
        int s = esrc[e[m]], d = edst[e[m]];
        av[m] = *(const uint4*)(abh + (size_t)s * 128 + q * 8);
        bv[m] = *(const uint4*)(abh + (size_t)d * 128 + 64 + q * 8);
    }
    float4 w[4];
#pragma unroll
    for (int j = 0; j < 4; ++j) w[j] = ((const float4*)(W2 + q * 16))[j];
    float c0 = b2[0], c1 = b2[1];

    float o0[4] = {0.f, 0.f, 0.f, 0.f}, o1[4] = {0.f, 0.f, 0.f, 0.f};
#pragma unroll
    for (int m = 0; m < 4; ++m) {
        const __half2* ah = (const __half2*)&av[m];
        const __half2* bh = (const __half2*)&bv[m];
#pragma unroll
        for (int j = 0; j < 4; ++j) {
            float2 aa = __half22float2(ah[j]);
            float2 bb = __half22float2(bh[j]);
            float h0 = fmaxf(aa.x + bb.x, 0.f);
            float h1 = fmaxf(aa.y + bb.y, 0.f);
            o0[m] = fmaf(h0, w[j].x, fmaf(h1, w[j].z, o0[m]));
            o1[m] = fmaf(h0, w[j].y, fmaf(h1, w[j].w, o1[m]));
        }
    }
#pragma unroll
    for (int m = 0; m < 4; ++m) {
#pragma unroll
        for (int sh = 4; sh >= 1; sh >>= 1) {
            o0[m] += __shfl_xor(o0[m], sh, 8);
            o1[m] += __shfl_xor(o1[m], sh, 8);
        }
    }
    if (q == 0) {
#pragma unroll
        for (int m = 0; m < 4; ++m)
            *(float2*)(out + (size_t)e[m] * 2) = make_float2(o0[m] + c0, o1[m] + c1);
    }
}

extern "C" void kernel_launch(void* const* d_in, const int* in_sizes, int n_in,
                              void* d_out, int out_size, void* d_ws, size_t ws_size,
                              hipStream_t stream) {
    (void)in_sizes; (void)n_in; (void)out_size; (void)ws_size;
    const float* x    = (const float*)d_in[0];
    const int*   ei   = (const int*)d_in[1];
    const float* ew   = (const float*)d_in[2];
    const int*   esrc = (const int*)d_in[3];
    const int*   edst = (const int*)d_in[4];
    const float* Wz   = (const float*)d_in[6];
    const float* bz   = (const float*)d_in[7];
    const float* lzW  = (const float*)d_in[8];
    const float* lzb  = (const float*)d_in[9];
    const float* Wh   = (const float*)d_in[14];
    const float* bh   = (const float*)d_in[15];
    const float* lhW  = (const float*)d_in[16];
    const float* lhb  = (const float*)d_in[17];
    const float* W1   = (const float*)d_in[18];
    const float* b1   = (const float*)d_in[19];
    const float* W2   = (const float*)d_in[20];
    const float* b2   = (const float*)d_in[21];
    float* out = (float*)d_out;

    float* ws = (float*)d_ws;
    float* bzp = ws;                                       // 64
    float* bhp = ws + 64;                                  // 64
    _Float16* Wct = (_Float16*)(ws + 128);                 // 12288 halves
    _Float16* W1t = (_Float16*)(ws + 6272);                // 8192 halves
    float*    dinv     = ws + 10368;                       // 100K
    int*      cnt      = (int*)(ws + 110368);              // 100K
    int*      rowstart = (int*)(ws + 210368);              // 100K
    unsigned* blockcounts = (unsigned*)(ws + 310368);      // 196*391 u32
    unsigned* buktot   = (unsigned*)(ws + 387008);         // 196
    unsigned* bukstart = (unsigned*)(ws + 387408);         // 197
    ushort*   yh   = (ushort*)(ws + 387808);               // 9.6M halves, 16B aligned
    ushort*   aggh = (ushort*)(ws + 5187808);              // 8M halves
    unsigned long long* bedges = (unsigned long long*)(ws + 9187808);  // 1.6M u64
    unsigned* csr = (unsigned*)(ws + 12387808);            // 1.6M u32
    ushort*   abh = (ushort*)(ws + 9187808);               // 12.8M halves (aliases bedges+csr)

    const int* g_src = ei;
    const int* g_dst = ei + NE;

    fuse_weights<<<dim3(128, 2), 128, 0, stream>>>(Wz, bz, lzW, lzb, Wh, bh, lhW, lhb,
                                                   W1, Wct, W1t, bzp, bhp);
    bucket_count<<<NBLKA, 256, 0, stream>>>(g_dst, blockcounts);
    bucket_scan_a<<<NBUK, 512, 0, stream>>>(blockcounts, buktot);
    bucket_scan_b<<<1, 256, 0, stream>>>(buktot, bukstart);
    bucket_scatter<<<NBLKA, 256, 0, stream>>>(g_src, g_dst, ew, blockcounts, bukstart, bedges);
    csr_build<<<NBUK, 512, 0, stream>>>(bedges, bukstart, csr, dinv, cnt, rowstart);
    build_y<<<(NN * 48 + 255) / 256, 256, 0, stream>>>(x, dinv, yh);
    gather_agg<<<(HALFN * 8 + 255) / 256, 256, 0, stream>>>(rowstart, cnt, csr, dinv, yh, aggh);
    node_kernel<<<512, 256, 0, stream>>>(aggh, Wct, W1t, bzp, bhp, b1, abh);
    edge_kernel<<<(NE / 4 * 8 + 255) / 256, 256, 0, stream>>>(abh, esrc, edst, W2, b2, out);
}

// Round 14
// 192.392 us; speedup vs baseline: 1.0743x; 1.0743x over previous
//
#include <hip/hip_runtime.h>
#include <hip/hip_bf16.h>
#include <hip/hip_fp16.h>

#define NN 100000
#define NE 1600000
#define FI 80
#define HD 64
#define NBUK 196   // ceil(NN/512) buckets of 512 nodes
#define BSH 9      // 512 nodes per bucket
#define NBLKA 391  // partition blocks; NBLKA*EPB >= NE
#define EPB 4096   // edges per partition block

typedef _Float16 f16x8 __attribute__((ext_vector_type(8)));
typedef float f32x4 __attribute__((ext_vector_type(4)));

// ---------------- fused weight precompute ----------------
// Wc_t[j][k] (fp16, [128][96], k>=80 zero): j<64: (Wz@lzW[0:64])[k][j]; j>=64: (Wh@lhW[0:64])[k][j-64]
// W1_t[j][k] (fp16, [128][64]): j<64: W1[k][j]; j>=64: W1[64+k][j-64]  (mlp_W1 is (128,64), stride 64)
// bzp/bhp = fused gate biases (f32).  (H=0 => R-gate dead; softmax(1)=1 => attention dead)
__global__ void fuse_weights(const float* __restrict__ Wz, const float* __restrict__ bz,
                             const float* __restrict__ lzW, const float* __restrict__ lzb,
                             const float* __restrict__ Wh, const float* __restrict__ bh,
                             const float* __restrict__ lhW, const float* __restrict__ lhb,
                             const float* __restrict__ W1,
                             _Float16* __restrict__ Wct, _Float16* __restrict__ W1t,
                             float* __restrict__ bzp, float* __restrict__ bhp) {
    int j = blockIdx.x;      // 0..127 output col
    int k = threadIdx.x;     // 0..127
    if (blockIdx.y == 1) {
        if (k < HD) {
            float v = (j < HD) ? W1[k * HD + j] : W1[(HD + k) * HD + (j - HD)];
            W1t[j * HD + k] = (_Float16)v;
        }
        return;
    }
    bool isZ = j < 64;
    int jj = isZ ? j : j - 64;
    const float* W = isZ ? Wz : Wh;
    const float* L = isZ ? lzW : lhW;
    if (k < FI) {
        float acc = 0.f;
        for (int i = 0; i < HD; ++i) acc = fmaf(W[k * HD + i], L[i * HD + jj], acc);
        Wct[j * 96 + k] = (_Float16)acc;
    } else if (k < 96) {
        Wct[j * 96 + k] = (_Float16)0.f;
    } else if (k == 96) {
        const float* bb = isZ ? bz : bh;
        const float* lb = isZ ? lzb : lhb;
        float acc = lb[jj];
        for (int i = 0; i < HD; ++i) acc = fmaf(bb[i], L[i * HD + jj], acc);
        (isZ ? bzp : bhp)[jj] = acc;
    }
}

// ---------------- radix-partition CSR build: ZERO global atomics ----------------
// (R11 diag: random returning atomics cap at ~25 Gops/s device-wide regardless of layout.)

// K1: per-block bucket histogram
__global__ __launch_bounds__(256) void bucket_count(const int* __restrict__ gdst,
                                                    unsigned* __restrict__ blockcounts) {
    __shared__ unsigned lcnt[NBUK];
    for (int i = threadIdx.x; i < NBUK; i += 256) lcnt[i] = 0;
    __syncthreads();
    int base = blockIdx.x * EPB;
#pragma unroll
    for (int i = 0; i < EPB / 256; ++i) {
        int e = base + i * 256 + threadIdx.x;
        if (e < NE) atomicAdd(&lcnt[(unsigned)gdst[e] >> BSH], 1u);
    }
    __syncthreads();
    for (int i = threadIdx.x; i < NBUK; i += 256)
        blockcounts[i * NBLKA + blockIdx.x] = lcnt[i];   // bucket-major
}

// K2a: per-bucket exclusive scan over blocks; emit bucket totals
__global__ __launch_bounds__(512) void bucket_scan_a(unsigned* __restrict__ blockcounts,
                                                     unsigned* __restrict__ buktot) {
    __shared__ unsigned s[512];
    int b = blockIdx.x, t = threadIdx.x;
    unsigned v = (t < NBLKA) ? blockcounts[b * NBLKA + t] : 0;
    s[t] = v;
    __syncthreads();
    for (int off = 1; off < 512; off <<= 1) {
        unsigned x = 0;
        if (t >= off) x = s[t - off];
        __syncthreads();
        s[t] += x;
        __syncthreads();
    }
    if (t < NBLKA) blockcounts[b * NBLKA + t] = s[t] - v;   // exclusive within bucket
    if (t == 511) buktot[b] = s[511];
}

// K2b: exclusive scan of bucket totals -> bukstart[0..NBUK]
__global__ void bucket_scan_b(const unsigned* __restrict__ buktot, unsigned* __restrict__ bukstart) {
    __shared__ unsigned s[256];
    int t = threadIdx.x;
    unsigned v = (t < NBUK) ? buktot[t] : 0;
    s[t] = v;
    __syncthreads();
    for (int off = 1; off < 256; off <<= 1) {
        unsigned x = 0;
        if (t >= off) x = s[t - off];
        __syncthreads();
        s[t] += x;
        __syncthreads();
    }
    if (t < NBUK) bukstart[t] = s[t] - v;
    if (t == NBUK - 1) bukstart[NBUK] = s[t];   // == NE
}

// K3: partition edges into bucket segments. payload: dl[9] | src[17] | ew_q20[20]
__global__ __launch_bounds__(256) void bucket_scatter(const int* __restrict__ gsrc,
                                                      const int* __restrict__ gdst,
                                                      const float* __restrict__ ew,
                                                      const unsigned* __restrict__ blockcounts,
                                                      const unsigned* __restrict__ bukstart,
                                                      unsigned long long* __restrict__ bedges) {
    __shared__ unsigned cur[NBUK];
    for (int i = threadIdx.x; i < NBUK; i += 256)
        cur[i] = bukstart[i] + blockcounts[i * NBLKA + blockIdx.x];
    __syncthreads();
    int base = blockIdx.x * EPB;
#pragma unroll
    for (int i = 0; i < EPB / 256; ++i) {
        int e = base + i * 256 + threadIdx.x;
        if (e < NE) {
            unsigned d = (unsigned)gdst[e];
            unsigned b = d >> BSH;
            unsigned pos = atomicAdd(&cur[b], 1u);                    // LDS atomic
            unsigned q20 = (unsigned)(ew[e] * 1048575.0f);            // floor, no src-field bleed
            unsigned long long pay = ((unsigned long long)(d & 511u) << 37) |
                                     ((unsigned long long)(unsigned)gsrc[e] << 20) |
                                     (unsigned long long)q20;
            bedges[pos] = pay;
        }
    }
}

// K4: per-bucket CSR build: LDS histogram+degsum -> LDS scan -> LDS-cursor scatter
__global__ __launch_bounds__(512) void csr_build(const unsigned long long* __restrict__ bedges,
                                                 const unsigned* __restrict__ bukstart,
                                                 unsigned* __restrict__ csr,
                                                 float* __restrict__ dinv,
                                                 int* __restrict__ cnt,
                                                 int* __restrict__ rowstart) {
    __shared__ unsigned lcnt[512];
    __shared__ unsigned ldeg[512];   // q20 fixed-point degree sum
    __shared__ unsigned lrow[512];
    int b = blockIdx.x, t = threadIdx.x;
    lcnt[t] = 0;
    ldeg[t] = 0;
    __syncthreads();
    unsigned beg = bukstart[b], end = bukstart[b + 1];
    for (unsigned i = beg + t; i < end; i += 512) {
        unsigned long long p = bedges[i];
        unsigned dl = (unsigned)(p >> 37);
        atomicAdd(&lcnt[dl], 1u);
        atomicAdd(&ldeg[dl], (unsigned)(p & 0xFFFFFu));
    }
    __syncthreads();
    unsigned v = lcnt[t];
    lrow[t] = v;
    __syncthreads();
    for (int off = 1; off < 512; off <<= 1) {
        unsigned x = 0;
        if (t >= off) x = lrow[t - off];
        __syncthreads();
        lrow[t] += x;
        __syncthreads();
    }
    unsigned myrow = lrow[t] - v;   // exclusive, bucket-relative
    __syncthreads();
    lrow[t] = beg + myrow;          // global cursor
    __syncthreads();
    for (unsigned i = beg + t; i < end; i += 512) {
        unsigned long long p = bedges[i];
        unsigned dl = (unsigned)(p >> 37);
        unsigned src = (unsigned)((p >> 20) & 0x1FFFFu);
        unsigned q15 = ((unsigned)(p & 0xFFFFFu)) >> 5;    // <= 32767
        unsigned pos = atomicAdd(&lrow[dl], 1u);           // LDS atomic
        csr[pos] = (src << 15) | q15;
    }
    int node = (b << BSH) + t;
    if (node < NN) {
        float deg = 1.0f + (float)ldeg[t] * (1.0f / 1048576.0f);
        dinv[node] = rsqrtf(deg);
        cnt[node] = (int)lcnt[t];
        rowstart[node] = (int)(beg + myrow);
    }
}

// ---------------- y table: y[n] = dinv[n]*x[n], fp16, rows padded to 96 halves ----------------
__global__ void build_y(const float* __restrict__ x, const float* __restrict__ dinv,
                        ushort* __restrict__ yh) {
    int i = blockIdx.x * 256 + threadIdx.x;   // over NN*48 half2
    if (i >= NN * 48) return;
    int n = i / 48, p = i % 48;
    float di = dinv[n];
    __half2 h;
    if (p < 40) {
        float2 vv = *(const float2*)(x + (size_t)n * FI + 2 * p);
        h = __floats2half2_rn(di * vv.x, di * vv.y);
    } else {
        h = __floats2half2_rn(0.f, 0.f);
    }
    *(__half2*)(yh + (size_t)n * 96 + 2 * p) = h;
}

// ---------------- gather aggregation: 8 lanes/node, UNROLL-2 software pipeline ----------------
// (R13 lesson: don't trade TLP for ILP — keep full wave count, issue 2 rows' loads
//  back-to-back inside one thread's loop instead. 2 rows = 6 lines in flight/group.)
__global__ __launch_bounds__(256) void gather_agg(const int* __restrict__ rowstart,
                                                  const int* __restrict__ cnt,
                                                  const unsigned* __restrict__ csr,
                                                  const float* __restrict__ dinv,
                                                  const ushort* __restrict__ yh,
                                                  ushort* __restrict__ aggh) {
    int t = blockIdx.x * 256 + threadIdx.x;
    int n = t >> 3, k = t & 7;
    if (n >= NN) return;
    float di = dinv[n];
    const ushort* yn = yh + (size_t)n * 96;
    float2 acc[5];
#pragma unroll
    for (int j = 0; j < 5; ++j)
        acc[j] = __half22float2(*(const __half2*)(yn + 2 * k + 16 * j));
    int i = rowstart[n], end = i + cnt[n];
    unsigned pA = (i < end) ? csr[i] : 0u;
    unsigned pB = (i + 1 < end) ? csr[i + 1] : 0u;
    while (i + 1 < end) {
        unsigned eA = pA, eB = pB;
        pA = (i + 2 < end) ? csr[i + 2] : 0u;
        pB = (i + 3 < end) ? csr[i + 3] : 0u;
        const ushort* ysA = yh + (size_t)(eA >> 15) * 96;
        const ushort* ysB = yh + (size_t)(eB >> 15) * 96;
        __half2 vA[5], vB[5];
#pragma unroll
        for (int j = 0; j < 5; ++j) vA[j] = *(const __half2*)(ysA + 2 * k + 16 * j);
#pragma unroll
        for (int j = 0; j < 5; ++j) vB[j] = *(const __half2*)(ysB + 2 * k + 16 * j);
        float wA = (float)(eA & 0x7FFFu) * (1.0f / 32767.0f);
        float wB = (float)(eB & 0x7FFFu) * (1.0f / 32767.0f);
#pragma unroll
        for (int j = 0; j < 5; ++j) {
            float2 fA = __half22float2(vA[j]);
            float2 fB = __half22float2(vB[j]);
            acc[j].x = fmaf(wA, fA.x, acc[j].x);
            acc[j].y = fmaf(wA, fA.y, acc[j].y);
            acc[j].x = fmaf(wB, fB.x, acc[j].x);
            acc[j].y = fmaf(wB, fB.y, acc[j].y);
        }
        i += 2;
    }
    if (i < end) {   // tail edge
        unsigned eA = pA;
        const ushort* ysA = yh + (size_t)(eA >> 15) * 96;
        float wA = (float)(eA & 0x7FFFu) * (1.0f / 32767.0f);
#pragma unroll
        for (int j = 0; j < 5; ++j) {
            float2 fA = __half22float2(*(const __half2*)(ysA + 2 * k + 16 * j));
            acc[j].x = fmaf(wA, fA.x, acc[j].x);
            acc[j].y = fmaf(wA, fA.y, acc[j].y);
        }
    }
    ushort* an = aggh + (size_t)n * FI;
#pragma unroll
    for (int j = 0; j < 5; ++j)
        *(__half2*)(an + 2 * k + 16 * j) = __floats2half2_rn(di * acc[j].x, di * acc[j].y);
}

// ---------------- node kernel: MFMA fp16 two-stage GEMM ----------------
// GEMM1: u(16x80,fp16) @ Wc(80x128) -> gates -> h(16x64);  GEMM2: h @ W1(64x128) -> ab fp16
// C-layout: col=lane&15, row=(lane>>4)*4+r (m89-verified); k-perm consistent on A/B sides.
__global__ __launch_bounds__(256) void node_kernel(const ushort* __restrict__ aggh,
        const _Float16* __restrict__ Wct, const _Float16* __restrict__ W1t,
        const float* __restrict__ bzp, const float* __restrict__ bhp,
        const float* __restrict__ b1, ushort* __restrict__ abh) {
    __shared__ __align__(16) _Float16 sWc[128 * 104];
    __shared__ __align__(16) _Float16 sW1[128 * 72];
    __shared__ __align__(16) _Float16 wbuf[4][2176];
    int tid = threadIdx.x;
    for (int i = tid; i < 1536; i += 256) {
        int col = i / 12, ko = (i % 12) * 8;
        *(uint4*)&sWc[col * 104 + ko] = ((const uint4*)Wct)[i];
    }
    for (int i = tid; i < 1024; i += 256) {
        int col = i / 8, ko = (i % 8) * 8;
        *(uint4*)&sW1[col * 72 + ko] = ((const uint4*)W1t)[i];
    }
    __syncthreads();

    int lane = tid & 63, wv = tid >> 6;
    int q = lane & 15, kg = lane >> 4;
    _Float16* hwb = wbuf[wv];

    float bzc[4], bhc[4], b1c[4];
#pragma unroll
    for (int t = 0; t < 4; ++t) {
        bzc[t] = bzp[q + 16 * t];
        bhc[t] = bhp[q + 16 * t];
        b1c[t] = b1[q + 16 * t];
    }

    const int NT = (NN + 63) >> 6;
    for (int tile = blockIdx.x; tile < NT; tile += gridDim.x) {
        int m0 = tile * 64 + wv * 16;
        int node = m0 + q;
        bool rv = node < NN;
        const _Float16* up = (const _Float16*)(aggh + (size_t)node * FI);
        f16x8 a1[3];
#pragma unroll
        for (int ks = 0; ks < 3; ++ks) {
            int kk = ks * 32 + kg * 8;
            a1[ks] = (rv && kk < FI) ? *(const f16x8*)(up + kk) : f16x8{};
        }
        f32x4 acc[8];
#pragma unroll
        for (int t = 0; t < 8; ++t) {
            const _Float16* wp = &sWc[(q + 16 * t) * 104 + kg * 8];
            f32x4 a = {0.f, 0.f, 0.f, 0.f};
            a = __builtin_amdgcn_mfma_f32_16x16x32_f16(a1[0], *(const f16x8*)(wp), a, 0, 0, 0);
            a = __builtin_amdgcn_mfma_f32_16x16x32_f16(a1[1], *(const f16x8*)(wp + 32), a, 0, 0, 0);
            a = __builtin_amdgcn_mfma_f32_16x16x32_f16(a1[2], *(const f16x8*)(wp + 64), a, 0, 0, 0);
            acc[t] = a;
        }
#pragma unroll
        for (int t = 0; t < 4; ++t) {
#pragma unroll
            for (int r = 0; r < 4; ++r) {
                float z = acc[t][r] + bzc[t];
                float p = acc[t + 4][r] + bhc[t];
                float Z = 1.f / (1.f + __expf(-z));
                float p2 = fminf(fmaxf(2.f * p, -60.f), 60.f);
                float e2 = __expf(p2);
                float Ht = (e2 - 1.f) / (e2 + 1.f);
                hwb[(kg * 4 + r) * 72 + q + 16 * t] = (_Float16)((1.f - Z) * Ht);
            }
        }
        f16x8 a2[2];
        a2[0] = *(const f16x8*)&hwb[q * 72 + kg * 8];
        a2[1] = *(const f16x8*)&hwb[q * 72 + 32 + kg * 8];
#pragma unroll
        for (int t = 0; t < 8; ++t) {
            const _Float16* wp = &sW1[(q + 16 * t) * 72 + kg * 8];
            f32x4 a = {0.f, 0.f, 0.f, 0.f};
            a = __builtin_amdgcn_mfma_f32_16x16x32_f16(a2[0], *(const f16x8*)(wp), a, 0, 0, 0);
            a = __builtin_amdgcn_mfma_f32_16x16x32_f16(a2[1], *(const f16x8*)(wp + 32), a, 0, 0, 0);
            float bb = (t < 4) ? b1c[t] : 0.f;
#pragma unroll
            for (int r = 0; r < 4; ++r)
                hwb[(kg * 4 + r) * 136 + q + 16 * t] = (_Float16)(a[r] + bb);
        }
#pragma unroll
        for (int i = lane; i < 256; i += 64) {
            int nd = i >> 4, off = (i & 15) * 8;
            int n2 = m0 + nd;
            if (n2 < NN)
                *(uint4*)(abh + (size_t)n2 * 128 + off) = *(const uint4*)&hwb[nd * 136 + off];
        }
    }
}

// ---------------- edge classifier: 8 lanes/edge, TWO edges per group (dual gather chains) ----------------
__global__ __launch_bounds__(256) void edge_kernel(const ushort* __restrict__ abh,
                                                   const int* __restrict__ esrc, const int* __restrict__ edst,
                                                   const float* __restrict__ W2, const float* __restrict__ b2,
                                                   float* __restrict__ out) {
    const int HALF = NE / 2;
    int t = blockIdx.x * 256 + threadIdx.x;
    int g = t >> 3, q = t & 7;
    if (g >= HALF) return;
    int e0 = g, e1 = g + HALF;
    int s0 = esrc[e0], d0 = edst[e0];
    int s1 = esrc[e1], d1 = edst[e1];
    uint4 a40 = *(const uint4*)(abh + (size_t)s0 * 128 + q * 8);
    uint4 b40 = *(const uint4*)(abh + (size_t)d0 * 128 + 64 + q * 8);
    uint4 a41 = *(const uint4*)(abh + (size_t)s1 * 128 + q * 8);
    uint4 b41 = *(const uint4*)(abh + (size_t)d1 * 128 + 64 + q * 8);
    float4 w[4];
#pragma unroll
    for (int j = 0; j < 4; ++j) w[j] = ((const float4*)(W2 + q * 16))[j];
    float c0 = b2[0], c1 = b2[1];

    float o00 = 0.f, o01 = 0.f, o10 = 0.f, o11 = 0.f;
    const __half2* ah0 = (const __half2*)&a40;
    const __half2* bh0 = (const __half2*)&b40;
    const __half2* ah1 = (const __half2*)&a41;
    const __half2* bh1 = (const __half2*)&b41;
#pragma unroll
    for (int j = 0; j < 4; ++j) {
        float2 av = __half22float2(ah0[j]);
        float2 bv = __half22float2(bh0[j]);
        float h0 = fmaxf(av.x + bv.x, 0.f);
        float h1 = fmaxf(av.y + bv.y, 0.f);
        o00 = fmaf(h0, w[j].x, fmaf(h1, w[j].z, o00));
        o01 = fmaf(h0, w[j].y, fmaf(h1, w[j].w, o01));
        float2 av1 = __half22float2(ah1[j]);
        float2 bv1 = __half22float2(bh1[j]);
        float g0 = fmaxf(av1.x + bv1.x, 0.f);
        float g1 = fmaxf(av1.y + bv1.y, 0.f);
        o10 = fmaf(g0, w[j].x, fmaf(g1, w[j].z, o10));
        o11 = fmaf(g0, w[j].y, fmaf(g1, w[j].w, o11));
    }
#pragma unroll
    for (int m = 4; m >= 1; m >>= 1) {
        o00 += __shfl_xor(o00, m, 8);
        o01 += __shfl_xor(o01, m, 8);
        o10 += __shfl_xor(o10, m, 8);
        o11 += __shfl_xor(o11, m, 8);
    }
    if (q == 0) {
        *(float2*)(out + (size_t)e0 * 2) = make_float2(o00 + c0, o01 + c1);
        *(float2*)(out + (size_t)e1 * 2) = make_float2(o10 + c0, o11 + c1);
    }
}

extern "C" void kernel_launch(void* const* d_in, const int* in_sizes, int n_in,
                              void* d_out, int out_size, void* d_ws, size_t ws_size,
                              hipStream_t stream) {
    (void)in_sizes; (void)n_in; (void)out_size; (void)ws_size;
    const float* x    = (const float*)d_in[0];
    const int*   ei   = (const int*)d_in[1];
    const float* ew   = (const float*)d_in[2];
    const int*   esrc = (const int*)d_in[3];
    const int*   edst = (const int*)d_in[4];
    const float* Wz   = (const float*)d_in[6];
    const float* bz   = (const float*)d_in[7];
    const float* lzW  = (const float*)d_in[8];
    const float* lzb  = (const float*)d_in[9];
    const float* Wh   = (const float*)d_in[14];
    const float* bh   = (const float*)d_in[15];
    const float* lhW  = (const float*)d_in[16];
    const float* lhb  = (const float*)d_in[17];
    const float* W1   = (const float*)d_in[18];
    const float* b1   = (const float*)d_in[19];
    const float* W2   = (const float*)d_in[20];
    const float* b2   = (const float*)d_in[21];
    float* out = (float*)d_out;

    float* ws = (float*)d_ws;
    float* bzp = ws;                                       // 64
    float* bhp = ws + 64;                                  // 64
    _Float16* Wct = (_Float16*)(ws + 128);                 // 12288 halves
    _Float16* W1t = (_Float16*)(ws + 6272);                // 8192 halves
    float*    dinv     = ws + 10368;                       // 100K
    int*      cnt      = (int*)(ws + 110368);              // 100K
    int*      rowstart = (int*)(ws + 210368);              // 100K
    unsigned* blockcounts = (unsigned*)(ws + 310368);      // 196*391 u32
    unsigned* buktot   = (unsigned*)(ws + 387008);         // 196
    unsigned* bukstart = (unsigned*)(ws + 387408);         // 197
    ushort*   yh   = (ushort*)(ws + 387808);               // 9.6M halves, 16B aligned
    ushort*   aggh = (ushort*)(ws + 5187808);              // 8M halves
    unsigned long long* bedges = (unsigned long long*)(ws + 9187808);  // 1.6M u64
    unsigned* csr = (unsigned*)(ws + 12387808);            // 1.6M u32
    ushort*   abh = (ushort*)(ws + 9187808);               // 12.8M halves (aliases bedges+csr)

    const int* g_src = ei;
    const int* g_dst = ei + NE;

    fuse_weights<<<dim3(128, 2), 128, 0, stream>>>(Wz, bz, lzW, lzb, Wh, bh, lhW, lhb,
                                                   W1, Wct, W1t, bzp, bhp);
    bucket_count<<<NBLKA, 256, 0, stream>>>(g_dst, blockcounts);
    bucket_scan_a<<<NBUK, 512, 0, stream>>>(blockcounts, buktot);
    bucket_scan_b<<<1, 256, 0, stream>>>(buktot, bukstart);
    bucket_scatter<<<NBLKA, 256, 0, stream>>>(g_src, g_dst, ew, blockcounts, bukstart, bedges);
    csr_build<<<NBUK, 512, 0, stream>>>(bedges, bukstart, csr, dinv, cnt, rowstart);
    build_y<<<(NN * 48 + 255) / 256, 256, 0, stream>>>(x, dinv, yh);
    gather_agg<<<(NN * 8 + 255) / 256, 256, 0, stream>>>(rowstart, cnt, csr, dinv, yh, aggh);
    node_kernel<<<512, 256, 0, stream>>>(aggh, Wct, W1t, bzp, bhp, b1, abh);
    edge_kernel<<<(NE / 2 * 8 + 255) / 256, 256, 0, stream>>>(abh, esrc, edst, W2, b2, out);
}